// Round 5
// baseline (268.921 us; speedup 1.0000x reference)
//
#include <hip/hip_runtime.h>
#include <hip/hip_bf16.h>

#define D64 64
#define NREL 16
#define SCALE 32.0f
#define INV_SCALE 0.03125f
#define PNB 256   // partition blocks

typedef __attribute__((ext_vector_type(8))) short bf16x8;
typedef __attribute__((ext_vector_type(4))) float f32x4;
typedef __attribute__((ext_vector_type(2))) float f32x2;

__device__ __forceinline__ float tanh_fast(float x) {
    float e = __expf(2.0f * x);
    return 1.0f - 2.0f / (e + 1.0f);
}

// Odd cubic fit of tanh (exact at x=0.5,1.0,1.5), clamp +-1.5. |x|<=1 err <=5e-4.
__device__ __forceinline__ float tanh_poly(float x) {
    x = fmaxf(-1.5f, fminf(1.5f, x));
    float u = x * x;
    float p = fmaf(u, -0.0182227f, 0.108952f);
    p = fmaf(u, p, -0.329139f);
    p = fmaf(u, p, 1.0f);
    return x * p;
}

__device__ __forceinline__ unsigned short f2b(float x) {
    __hip_bfloat16 h = __float2bfloat16(x);
    return *reinterpret_cast<unsigned short*>(&h);
}

// R12 (kept): prep writes Wt directly in MFMA *fragment order*:
//   Wt2[r*4096 + mt*1024 + q2*512 + ln*8 + j] = bf16(32 * WR[r][d][c])
//   with c = mt*16 + (ln&15), d = q2*32 + (ln>>4)*8 + j.
// relp k-permuted: kp = q*16 + m*4 + g <-> k = m*16 + q*4 + g.
// Also zeroes denom (grid covers n_nodes).
__global__ void prep_kernel(const float* __restrict__ WR, const float* __restrict__ rel,
                            unsigned short* __restrict__ Wt, float* __restrict__ relp,
                            float* __restrict__ denom, int n_nodes) {
    int i = blockIdx.x * blockDim.x + threadIdx.x;
    if (i < NREL * D64 * D64) {
        int r = i >> 12, mt = (i >> 10) & 3, q2 = (i >> 9) & 1;
        int ln = (i >> 3) & 63, j = i & 7;
        int c = mt * 16 + (ln & 15);
        int d = q2 * 32 + ((ln >> 4) << 3) + j;
        Wt[i] = f2b(WR[(r << 12) + (d << 6) + c] * SCALE);
    }
    if (i < NREL * D64) {
        int t = i >> 6, kp = i & 63;
        int q = kp >> 4, m = (kp >> 2) & 3, g = kp & 3;
        relp[i] = rel[t * D64 + m * 16 + q * 4 + g];
    }
    if (i < n_nodes) denom[i] = 0.0f;
}

// R12 (kept): NO LDS, NO barrier. Wt fragment-ordered, L2-resident; waves load
// A-fragments straight from global. Store layout byte-identical to R6..R13:
// stored kp = quad*16 + mt*4 + reg  <->  true k = mt*16 + quad*4 + reg.
__global__ __launch_bounds__(256, 3)
void trans_gemm_kernel(const float* __restrict__ emb,
                       const unsigned short* __restrict__ Wt,
                       uint4* __restrict__ trans,   // [r][node] rows of 4 x uint4
                       int n_nodes) {
    const int tid  = threadIdx.x;
    const int lane = tid & 63;
    const int wid  = tid >> 6;
    const int col  = lane & 15;
    const int quad = lane >> 4;
    const int rbase = (blockIdx.x & 1) * 8;
    const int nodebase = (blockIdx.x >> 1) * 256 + wid * 64;

    bf16x8 bfr[4][2];
    int nds[4];
    #pragma unroll
    for (int j = 0; j < 4; ++j) {
        int node = nodebase + j * 16 + col;
        nds[j] = node;
        int cn = node < n_nodes ? node : n_nodes - 1;
        const float* bp = emb + (size_t)cn * D64 + quad * 8;
        #pragma unroll
        for (int ks = 0; ks < 2; ++ks) {
            float4 v0 = *(const float4*)(bp + ks * 32);
            float4 v1 = *(const float4*)(bp + ks * 32 + 4);
            bfr[j][ks][0] = (short)f2b(v0.x); bfr[j][ks][1] = (short)f2b(v0.y);
            bfr[j][ks][2] = (short)f2b(v0.z); bfr[j][ks][3] = (short)f2b(v0.w);
            bfr[j][ks][4] = (short)f2b(v1.x); bfr[j][ks][5] = (short)f2b(v1.y);
            bfr[j][ks][6] = (short)f2b(v1.z); bfr[j][ks][7] = (short)f2b(v1.w);
        }
    }

    const unsigned short* wb = Wt + (rbase << 12) + (lane << 3);

    #pragma unroll 1
    for (int rr = 0; rr < 8; ++rr) {
        const int r = rbase + rr;
        const unsigned short* lb = wb + (rr << 12);
        f32x4 acc[4][4];   // [mt][j]
        #pragma unroll
        for (int mt = 0; mt < 4; ++mt) {
            bf16x8 a0 = *(const bf16x8*)(lb + (mt << 10));
            bf16x8 a1 = *(const bf16x8*)(lb + (mt << 10) + 512);
            #pragma unroll
            for (int j = 0; j < 4; ++j) {
                f32x4 c = {0.f, 0.f, 0.f, 0.f};
                c = __builtin_amdgcn_mfma_f32_16x16x32_bf16(a0, bfr[j][0], c, 0, 0, 0);
                c = __builtin_amdgcn_mfma_f32_16x16x32_bf16(a1, bfr[j][1], c, 0, 0, 0);
                acc[mt][j] = c;
            }
        }
        #pragma unroll
        for (int j = 0; j < 4; ++j) {
            if (nds[j] < n_nodes) {
                uint4 pk;
                unsigned p;
                p = __builtin_amdgcn_cvt_pk_fp8_f32(acc[0][j][0], acc[0][j][1], 0, false);
                p = __builtin_amdgcn_cvt_pk_fp8_f32(acc[0][j][2], acc[0][j][3], p, true);
                pk.x = p;
                p = __builtin_amdgcn_cvt_pk_fp8_f32(acc[1][j][0], acc[1][j][1], 0, false);
                p = __builtin_amdgcn_cvt_pk_fp8_f32(acc[1][j][2], acc[1][j][3], p, true);
                pk.y = p;
                p = __builtin_amdgcn_cvt_pk_fp8_f32(acc[2][j][0], acc[2][j][1], 0, false);
                p = __builtin_amdgcn_cvt_pk_fp8_f32(acc[2][j][2], acc[2][j][3], p, true);
                pk.z = p;
                p = __builtin_amdgcn_cvt_pk_fp8_f32(acc[3][j][0], acc[3][j][1], 0, false);
                p = __builtin_amdgcn_cvt_pk_fp8_f32(acc[3][j][2], acc[3][j][3], p, true);
                pk.w = p;
                trans[((size_t)r * n_nodes + nds[j]) * 4 + quad] = pk;
            }
        }
    }
}

// 4 fp8 terms: acc += t * tanh(h*INV_SCALE + rel)   (t,h pre-scaled by SCALE)
__device__ __forceinline__ void term4(unsigned ut, unsigned uh, float4 r, float& acc) {
    f32x2 tlo = __builtin_amdgcn_cvt_pk_f32_fp8(ut, false);
    f32x2 thi = __builtin_amdgcn_cvt_pk_f32_fp8(ut, true);
    f32x2 hlo = __builtin_amdgcn_cvt_pk_f32_fp8(uh, false);
    f32x2 hhi = __builtin_amdgcn_cvt_pk_f32_fp8(uh, true);
    acc += tlo[0] * tanh_poly(fmaf(hlo[0], INV_SCALE, r.x));
    acc += tlo[1] * tanh_poly(fmaf(hlo[1], INV_SCALE, r.y));
    acc += thi[0] * tanh_poly(fmaf(hhi[0], INV_SCALE, r.z));
    acc += thi[1] * tanh_poly(fmaf(hhi[1], INV_SCALE, r.w));
}

// ---------------- R16: type-bucket partition (3 small kernels) --------------
// Order within a bucket is irrelevant: each edge carries its original index
// (out[] scatter) and denom is atomic. So an UNSTABLE counting sort suffices.

__global__ __launch_bounds__(256)
void hist_kernel(const int* __restrict__ etype, int* __restrict__ cnt,
                 int E, int chunk) {
    __shared__ int h[NREL];
    int tid = threadIdx.x;
    if (tid < NREL) h[tid] = 0;
    __syncthreads();
    int beg = blockIdx.x * chunk;
    int end = beg + chunk; if (end > E) end = E;
    for (int e = beg + tid; e < end; e += 256)
        atomicAdd(&h[etype[e]], 1);
    __syncthreads();
    if (tid < NREL) cnt[blockIdx.x * NREL + tid] = h[tid];
}

// Single block: exclusive scan of cnt[PNB][16] -> base[PNB][16] (bucket-major).
// All arithmetic from LDS (16 KB) — coalesced load/store, ~2us.
__global__ __launch_bounds__(256)
void scan_kernel(const int* __restrict__ cnt, int* __restrict__ base) {
    __shared__ int lc[PNB * NREL];
    __shared__ int tt[NREL], tb[NREL];
    int tid = threadIdx.x;
    for (int i = tid; i < PNB * NREL; i += 256) lc[i] = cnt[i];
    __syncthreads();
    if (tid < NREL) {
        int s = 0;
        for (int b = 0; b < PNB; ++b) s += lc[b * NREL + tid];
        tt[tid] = s;
    }
    __syncthreads();
    if (tid == 0) {
        int run = 0;
        for (int t = 0; t < NREL; ++t) { tb[t] = run; run += tt[t]; }
    }
    __syncthreads();
    if (tid < NREL) {
        int run = tb[tid];
        for (int b = 0; b < PNB; ++b) {
            int c = lc[b * NREL + tid];
            lc[b * NREL + tid] = run;
            run += c;
        }
    }
    __syncthreads();
    for (int i = tid; i < PNB * NREL; i += 256) base[i] = lc[i];
}

__global__ __launch_bounds__(256)
void scatter_kernel(const int* __restrict__ esrc, const int* __restrict__ edst,
                    const int* __restrict__ etype, const int* __restrict__ base,
                    int* __restrict__ bsrc, int* __restrict__ bdst,
                    int* __restrict__ btype, int* __restrict__ borig,
                    int E, int chunk) {
    __shared__ int cur[NREL];
    int tid = threadIdx.x;
    if (tid < NREL) cur[tid] = base[blockIdx.x * NREL + tid];
    __syncthreads();
    int beg = blockIdx.x * chunk;
    int end = beg + chunk; if (end > E) end = E;
    for (int e = beg + tid; e < end; e += 256) {
        int t = etype[e];
        int pos = atomicAdd(&cur[t], 1);   // LDS atomic: unique pos, unordered
        bsrc[pos]  = esrc[e];
        bdst[pos]  = edst[e];
        btype[pos] = t;
        borig[pos] = e;
    }
}

// R16: bucketed edge kernel. Same verified 2-edge/16-gather structure as R13
// (108 VGPR, no launch-bounds pressure), but edges arrive type-contiguous:
// consecutive blocks gather from ONE 7.68 MB relation slice instead of the
// full 123 MB table -> gathers served by L3 (slice-resident) and partly L2.
// Mechanism: per-CU request queue is fixed (~54; R14/R15 proved SW can't
// deepen it), so throughput = depth/latency -> cut latency via locality.
// XCD-chunk swizzle (bijective: grid padded to %8==0): consecutive work
// blocks land on the SAME XCD so same-slice blocks share that XCD's 4MB L2.
// Output scattered via borig; denom atomic (order-independent).
__global__ __launch_bounds__(256)
void edge_bucketed_kernel(const unsigned* __restrict__ trans,
                          const float* __restrict__ relp,
                          const int* __restrict__ bsrc, const int* __restrict__ bdst,
                          const int* __restrict__ btype, const int* __restrict__ borig,
                          float* __restrict__ out, float* __restrict__ denom,
                          int E, int n_nodes) {
    int q = gridDim.x >> 3;                       // grid padded to multiple of 8
    int wg = ((int)blockIdx.x & 7) * q + ((int)blockIdx.x >> 3);
    int e0 = wg * 512 + threadIdx.x;
    int e1 = e0 + 256;
    bool v0 = e0 < E, v1 = e1 < E;
    int i0 = v0 ? e0 : 0;
    int i1 = v1 ? e1 : 0;
    int t0 = btype[i0], s0 = bsrc[i0], d0 = bdst[i0], o0 = borig[i0];
    int t1 = btype[i1], s1 = bsrc[i1], d1 = bdst[i1], o1 = borig[i1];

    const uint4* tb = (const uint4*)trans;
    unsigned nn = (unsigned)n_nodes;
    unsigned rt0 = ((unsigned)t0 * nn + (unsigned)s0) * 4u;
    unsigned rh0 = ((unsigned)t0 * nn + (unsigned)d0) * 4u;
    unsigned rt1 = ((unsigned)t1 * nn + (unsigned)s1) * 4u;
    unsigned rh1 = ((unsigned)t1 * nn + (unsigned)d1) * 4u;

    uint4 T0[4], H0[4], T1[4], H1[4];
    #pragma unroll
    for (int c4 = 0; c4 < 4; ++c4) {
        T0[c4] = tb[rt0 + c4]; H0[c4] = tb[rh0 + c4];
        T1[c4] = tb[rt1 + c4]; H1[c4] = tb[rh1 + c4];
    }

    const float4* pr0 = (const float4*)(relp + t0 * D64);
    const float4* pr1 = (const float4*)(relp + t1 * D64);
    float a0 = 0.f, a1 = 0.f;
    #pragma unroll
    for (int c4 = 0; c4 < 4; ++c4) {
        term4(T0[c4].x, H0[c4].x, pr0[c4 * 4 + 0], a0);
        term4(T1[c4].x, H1[c4].x, pr1[c4 * 4 + 0], a1);
        term4(T0[c4].y, H0[c4].y, pr0[c4 * 4 + 1], a0);
        term4(T1[c4].y, H1[c4].y, pr1[c4 * 4 + 1], a1);
        term4(T0[c4].z, H0[c4].z, pr0[c4 * 4 + 2], a0);
        term4(T1[c4].z, H1[c4].z, pr1[c4 * 4 + 2], a1);
        term4(T0[c4].w, H0[c4].w, pr0[c4 * 4 + 3], a0);
        term4(T1[c4].w, H1[c4].w, pr1[c4 * 4 + 3], a1);
    }
    if (v0) {
        float ex = __expf(a0 * INV_SCALE);
        out[o0] = ex;
        atomicAdd(&denom[d0], ex);
    }
    if (v1) {
        float ex = __expf(a1 * INV_SCALE);
        out[o1] = ex;
        atomicAdd(&denom[d1], ex);
    }
}

// R13 edge kernel kept as the no-bucket-workspace fallback path.
__global__ __launch_bounds__(256)
void edge_kernel(const unsigned* __restrict__ trans,
                 const float* __restrict__ relp,
                 const int* __restrict__ esrc, const int* __restrict__ edst,
                 const int* __restrict__ etype,
                 float* __restrict__ out, float* __restrict__ denom,
                 int E, int n_nodes) {
    int e0 = blockIdx.x * 512 + threadIdx.x;
    int e1 = e0 + 256;
    bool v0 = e0 < E, v1 = e1 < E;
    int i0 = v0 ? e0 : 0;
    int i1 = v1 ? e1 : 0;
    int t0 = etype[i0], s0 = esrc[i0], d0 = edst[i0];
    int t1 = etype[i1], s1 = esrc[i1], d1 = edst[i1];

    const uint4* tb = (const uint4*)trans;
    unsigned nn = (unsigned)n_nodes;
    unsigned rt0 = ((unsigned)t0 * nn + (unsigned)s0) * 4u;
    unsigned rh0 = ((unsigned)t0 * nn + (unsigned)d0) * 4u;
    unsigned rt1 = ((unsigned)t1 * nn + (unsigned)s1) * 4u;
    unsigned rh1 = ((unsigned)t1 * nn + (unsigned)d1) * 4u;

    uint4 T0[4], H0[4], T1[4], H1[4];
    #pragma unroll
    for (int c4 = 0; c4 < 4; ++c4) {
        T0[c4] = tb[rt0 + c4]; H0[c4] = tb[rh0 + c4];
        T1[c4] = tb[rt1 + c4]; H1[c4] = tb[rh1 + c4];
    }

    const float4* pr0 = (const float4*)(relp + t0 * D64);
    const float4* pr1 = (const float4*)(relp + t1 * D64);
    float a0 = 0.f, a1 = 0.f;
    #pragma unroll
    for (int c4 = 0; c4 < 4; ++c4) {
        term4(T0[c4].x, H0[c4].x, pr0[c4 * 4 + 0], a0);
        term4(T1[c4].x, H1[c4].x, pr1[c4 * 4 + 0], a1);
        term4(T0[c4].y, H0[c4].y, pr0[c4 * 4 + 1], a0);
        term4(T1[c4].y, H1[c4].y, pr1[c4 * 4 + 1], a1);
        term4(T0[c4].z, H0[c4].z, pr0[c4 * 4 + 2], a0);
        term4(T1[c4].z, H1[c4].z, pr1[c4 * 4 + 2], a1);
        term4(T0[c4].w, H0[c4].w, pr0[c4 * 4 + 3], a0);
        term4(T1[c4].w, H1[c4].w, pr1[c4 * 4 + 3], a1);
    }
    if (v0) {
        float ex = __expf(a0 * INV_SCALE);
        out[e0] = ex;
        atomicAdd(&denom[d0], ex);
    }
    if (v1) {
        float ex = __expf(a1 * INV_SCALE);
        out[e1] = ex;
        atomicAdd(&denom[d1], ex);
    }
}

__global__ void normalize_kernel(float* __restrict__ out,
                                 const float* __restrict__ denom,
                                 const int* __restrict__ edst, int E) {
    int e = blockIdx.x * blockDim.x + threadIdx.x;
    if (e < E) out[e] = out[e] / denom[edst[e]];
}

// ---------------- fallback (R1 structure) if ws is too small ----------------
__global__ void zero_denom_kernel(float* __restrict__ denom, int n) {
    int i = blockIdx.x * blockDim.x + threadIdx.x;
    if (i < n) denom[i] = 0.0f;
}

__global__ __launch_bounds__(256)
void edge_att_fallback(const float* __restrict__ emb, const float* __restrict__ rel,
                       const float* __restrict__ WR, const int* __restrict__ esrc,
                       const int* __restrict__ edst, const int* __restrict__ etype,
                       float* __restrict__ exbuf, float* __restrict__ denom,
                       int E, int chunkSize) {
    const int type = blockIdx.x & 15;
    const int c    = blockIdx.x >> 4;
    const int lane = threadIdx.x & 63;
    const int wid  = threadIdx.x >> 6;
    long base0 = (long)c * (long)chunkSize;
    long cend  = base0 + chunkSize;
    if (cend > E) cend = E;
    if (base0 >= cend) return;
    int per = (chunkSize + 3) >> 2;
    long wbeg = base0 + (long)wid * per;
    long wend = wbeg + per;
    if (wend > cend) wend = cend;
    if (wbeg >= wend) return;
    float w[D64];
    const float* Wt = WR + (size_t)type * D64 * D64;
    #pragma unroll
    for (int d = 0; d < D64; ++d) w[d] = Wt[d * D64 + lane];
    const float rk = rel[type * D64 + lane];
    for (long s0 = wbeg; s0 < wend; s0 += 64) {
        long e = s0 + lane;
        int ty = -1, sv = 0, dv = 0;
        if (e < wend) { ty = etype[e]; sv = esrc[e]; dv = edst[e]; }
        unsigned long long m = __ballot(ty == type);
        while (m) {
            int b = __builtin_ctzll(m);
            m &= m - 1;
            int sn = __builtin_amdgcn_readlane(sv, b);
            int dn = __builtin_amdgcn_readlane(dv, b);
            const float4* es4 = (const float4*)(emb + (size_t)sn * D64);
            const float4* ed4 = (const float4*)(emb + (size_t)dn * D64);
            float t0 = 0.f, t1 = 0.f, t2 = 0.f, t3 = 0.f;
            float h0 = 0.f, h1 = 0.f, h2 = 0.f, h3 = 0.f;
            #pragma unroll
            for (int i = 0; i < D64 / 4; ++i) {
                float4 a = es4[i]; float4 b4 = ed4[i];
                t0 = fmaf(a.x, w[4*i+0], t0); t1 = fmaf(a.y, w[4*i+1], t1);
                t2 = fmaf(a.z, w[4*i+2], t2); t3 = fmaf(a.w, w[4*i+3], t3);
                h0 = fmaf(b4.x, w[4*i+0], h0); h1 = fmaf(b4.y, w[4*i+1], h1);
                h2 = fmaf(b4.z, w[4*i+2], h2); h3 = fmaf(b4.w, w[4*i+3], h3);
            }
            float t = (t0 + t1) + (t2 + t3);
            float h = (h0 + h1) + (h2 + h3);
            float p = t * tanh_fast(h + rk);
            #pragma unroll
            for (int off = 32; off > 0; off >>= 1) p += __shfl_xor(p, off);
            if (lane == 0) {
                float ex = __expf(p);
                exbuf[s0 + b] = ex;
                atomicAdd(&denom[dn], ex);
            }
        }
    }
}

__global__ void normalize_fallback(float* __restrict__ out,
                                   const float* __restrict__ denom,
                                   const int* __restrict__ edst, int E) {
    int e = blockIdx.x * blockDim.x + threadIdx.x;
    if (e < E) out[e] = out[e] / denom[edst[e]];
}
// ---------------------------------------------------------------------------

extern "C" void kernel_launch(void* const* d_in, const int* in_sizes, int n_in,
                              void* d_out, int out_size, void* d_ws, size_t ws_size,
                              hipStream_t stream) {
    const float* emb  = (const float*)d_in[0];   // [n_nodes, 64]
    const float* rel  = (const float*)d_in[1];   // [16, 64]
    const float* WR   = (const float*)d_in[2];   // [16, 64, 64]
    const int*   esrc = (const int*)d_in[3];     // [E]
    const int*   edst = (const int*)d_in[4];     // [E]
    const int*   ety  = (const int*)d_in[5];     // [E]

    const int E       = in_sizes[3];
    const int n_nodes = in_sizes[0] / D64;
    float* out = (float*)d_out;

    // workspace carve (256-B aligned); basic part identical to R7..R13 layout
    size_t transB = (size_t)NREL * n_nodes * D64;            // fp8 bytes
    size_t off_trans = 0;
    size_t off_wt    = (off_trans + transB + 255) & ~(size_t)255;
    size_t off_rel   = (off_wt + (size_t)NREL * D64 * D64 * 2 + 255) & ~(size_t)255;
    size_t off_den   = (off_rel + (size_t)NREL * D64 * 4 + 255) & ~(size_t)255;
    size_t need_basic = off_den + (size_t)n_nodes * sizeof(float);
    // bucket extension
    size_t off_bsrc  = (need_basic + 255) & ~(size_t)255;
    size_t off_bdst  = (off_bsrc + (size_t)E * 4 + 255) & ~(size_t)255;
    size_t off_btyp  = (off_bdst + (size_t)E * 4 + 255) & ~(size_t)255;
    size_t off_borg  = (off_btyp + (size_t)E * 4 + 255) & ~(size_t)255;
    size_t off_cnt   = (off_borg + (size_t)E * 4 + 255) & ~(size_t)255;
    size_t off_base  = (off_cnt + (size_t)PNB * NREL * 4 + 255) & ~(size_t)255;
    size_t need_bucket = off_base + (size_t)PNB * NREL * 4;

    if (ws_size >= need_basic) {
        uint4*          trans = (uint4*)((char*)d_ws + off_trans);
        unsigned short* Wt    = (unsigned short*)((char*)d_ws + off_wt);
        float*          relp  = (float*)((char*)d_ws + off_rel);
        float*          denom = (float*)((char*)d_ws + off_den);

        int prepN = n_nodes > NREL * D64 * D64 ? n_nodes : NREL * D64 * D64;
        prep_kernel<<<(prepN + 255) / 256, 256, 0, stream>>>(WR, rel, Wt, relp,
                                                             denom, n_nodes);
        trans_gemm_kernel<<<((n_nodes + 255) / 256) * 2, 256, 0, stream>>>(emb, Wt, trans, n_nodes);

        if (ws_size >= need_bucket) {
            int* bsrc  = (int*)((char*)d_ws + off_bsrc);
            int* bdst  = (int*)((char*)d_ws + off_bdst);
            int* btyp  = (int*)((char*)d_ws + off_btyp);
            int* borg  = (int*)((char*)d_ws + off_borg);
            int* cnt   = (int*)((char*)d_ws + off_cnt);
            int* base  = (int*)((char*)d_ws + off_base);
            int chunk  = (E + PNB - 1) / PNB;
            hist_kernel<<<PNB, 256, 0, stream>>>(ety, cnt, E, chunk);
            scan_kernel<<<1, 256, 0, stream>>>(cnt, base);
            scatter_kernel<<<PNB, 256, 0, stream>>>(esrc, edst, ety, base,
                                                    bsrc, bdst, btyp, borg, E, chunk);
            int gb = (E + 511) / 512;
            int gpad = ((gb + 7) / 8) * 8;   // bijective XCD swizzle needs %8==0
            edge_bucketed_kernel<<<gpad, 256, 0, stream>>>((const unsigned*)trans, relp,
                                                           bsrc, bdst, btyp, borg,
                                                           out, denom, E, n_nodes);
        } else {
            edge_kernel<<<(E + 511) / 512, 256, 0, stream>>>((const unsigned*)trans, relp,
                                                             esrc, edst, ety,
                                                             out, denom, E, n_nodes);
        }
        normalize_kernel<<<(E + 255) / 256, 256, 0, stream>>>(out, denom, edst, E);
    } else {
        float* denom = (float*)d_ws;   // [n_nodes]
        zero_denom_kernel<<<(n_nodes + 255) / 256, 256, 0, stream>>>(denom, n_nodes);
        const int NCHUNK = 256;
        int chunk = (E + NCHUNK - 1) / NCHUNK;
        edge_att_fallback<<<16 * NCHUNK, 256, 0, stream>>>(emb, rel, WR, esrc, edst, ety,
                                                           out, denom, E, chunk);
        normalize_fallback<<<(E + 255) / 256, 256, 0, stream>>>(out, denom, edst, E);
    }
}

// Round 6
// 225.327 us; speedup vs baseline: 1.1935x; 1.1935x over previous
//
#include <hip/hip_runtime.h>
#include <hip/hip_bf16.h>

#define D64 64
#define NREL 16
#define SCALE 32.0f
#define INV_SCALE 0.03125f

typedef __attribute__((ext_vector_type(8))) short bf16x8;
typedef __attribute__((ext_vector_type(4))) float f32x4;
typedef __attribute__((ext_vector_type(2))) float f32x2;
typedef __attribute__((ext_vector_type(4))) unsigned int u32x4;

__device__ __forceinline__ float tanh_fast(float x) {
    float e = __expf(2.0f * x);
    return 1.0f - 2.0f / (e + 1.0f);
}

// Odd cubic fit of tanh (exact at x=0.5,1.0,1.5), clamp +-1.5. |x|<=1 err <=5e-4.
__device__ __forceinline__ float tanh_poly(float x) {
    x = fmaxf(-1.5f, fminf(1.5f, x));
    float u = x * x;
    float p = fmaf(u, -0.0182227f, 0.108952f);
    p = fmaf(u, p, -0.329139f);
    p = fmaf(u, p, 1.0f);
    return x * p;
}

__device__ __forceinline__ unsigned short f2b(float x) {
    __hip_bfloat16 h = __float2bfloat16(x);
    return *reinterpret_cast<unsigned short*>(&h);
}

// R12 (kept): prep writes Wt directly in MFMA *fragment order*:
//   Wt2[r*4096 + mt*1024 + q2*512 + ln*8 + j] = bf16(32 * WR[r][d][c])
//   with c = mt*16 + (ln&15), d = q2*32 + (ln>>4)*8 + j.
// relp k-permuted: kp = q*16 + m*4 + g <-> k = m*16 + q*4 + g.
// Also zeroes denom (grid covers n_nodes).
__global__ void prep_kernel(const float* __restrict__ WR, const float* __restrict__ rel,
                            unsigned short* __restrict__ Wt, float* __restrict__ relp,
                            float* __restrict__ denom, int n_nodes) {
    int i = blockIdx.x * blockDim.x + threadIdx.x;
    if (i < NREL * D64 * D64) {
        int r = i >> 12, mt = (i >> 10) & 3, q2 = (i >> 9) & 1;
        int ln = (i >> 3) & 63, j = i & 7;
        int c = mt * 16 + (ln & 15);
        int d = q2 * 32 + ((ln >> 4) << 3) + j;
        Wt[i] = f2b(WR[(r << 12) + (d << 6) + c] * SCALE);
    }
    if (i < NREL * D64) {
        int t = i >> 6, kp = i & 63;
        int q = kp >> 4, m = (kp >> 2) & 3, g = kp & 3;
        relp[i] = rel[t * D64 + m * 16 + q * 4 + g];
    }
    if (i < n_nodes) denom[i] = 0.0f;
}

// R12 (kept): NO LDS, NO barrier. Wt fragment-ordered, L2-resident; waves load
// A-fragments straight from global. Store layout byte-identical to R6..R13:
// stored kp = quad*16 + mt*4 + reg  <->  true k = mt*16 + quad*4 + reg.
__global__ __launch_bounds__(256, 3)
void trans_gemm_kernel(const float* __restrict__ emb,
                       const unsigned short* __restrict__ Wt,
                       uint4* __restrict__ trans,   // [r][node] rows of 4 x uint4
                       int n_nodes) {
    const int tid  = threadIdx.x;
    const int lane = tid & 63;
    const int wid  = tid >> 6;
    const int col  = lane & 15;
    const int quad = lane >> 4;
    const int rbase = (blockIdx.x & 1) * 8;
    const int nodebase = (blockIdx.x >> 1) * 256 + wid * 64;

    bf16x8 bfr[4][2];
    int nds[4];
    #pragma unroll
    for (int j = 0; j < 4; ++j) {
        int node = nodebase + j * 16 + col;
        nds[j] = node;
        int cn = node < n_nodes ? node : n_nodes - 1;
        const float* bp = emb + (size_t)cn * D64 + quad * 8;
        #pragma unroll
        for (int ks = 0; ks < 2; ++ks) {
            float4 v0 = *(const float4*)(bp + ks * 32);
            float4 v1 = *(const float4*)(bp + ks * 32 + 4);
            bfr[j][ks][0] = (short)f2b(v0.x); bfr[j][ks][1] = (short)f2b(v0.y);
            bfr[j][ks][2] = (short)f2b(v0.z); bfr[j][ks][3] = (short)f2b(v0.w);
            bfr[j][ks][4] = (short)f2b(v1.x); bfr[j][ks][5] = (short)f2b(v1.y);
            bfr[j][ks][6] = (short)f2b(v1.z); bfr[j][ks][7] = (short)f2b(v1.w);
        }
    }

    const unsigned short* wb = Wt + (rbase << 12) + (lane << 3);

    #pragma unroll 1
    for (int rr = 0; rr < 8; ++rr) {
        const int r = rbase + rr;
        const unsigned short* lb = wb + (rr << 12);
        f32x4 acc[4][4];   // [mt][j]
        #pragma unroll
        for (int mt = 0; mt < 4; ++mt) {
            bf16x8 a0 = *(const bf16x8*)(lb + (mt << 10));
            bf16x8 a1 = *(const bf16x8*)(lb + (mt << 10) + 512);
            #pragma unroll
            for (int j = 0; j < 4; ++j) {
                f32x4 c = {0.f, 0.f, 0.f, 0.f};
                c = __builtin_amdgcn_mfma_f32_16x16x32_bf16(a0, bfr[j][0], c, 0, 0, 0);
                c = __builtin_amdgcn_mfma_f32_16x16x32_bf16(a1, bfr[j][1], c, 0, 0, 0);
                acc[mt][j] = c;
            }
        }
        #pragma unroll
        for (int j = 0; j < 4; ++j) {
            if (nds[j] < n_nodes) {
                uint4 pk;
                unsigned p;
                p = __builtin_amdgcn_cvt_pk_fp8_f32(acc[0][j][0], acc[0][j][1], 0, false);
                p = __builtin_amdgcn_cvt_pk_fp8_f32(acc[0][j][2], acc[0][j][3], p, true);
                pk.x = p;
                p = __builtin_amdgcn_cvt_pk_fp8_f32(acc[1][j][0], acc[1][j][1], 0, false);
                p = __builtin_amdgcn_cvt_pk_fp8_f32(acc[1][j][2], acc[1][j][3], p, true);
                pk.y = p;
                p = __builtin_amdgcn_cvt_pk_fp8_f32(acc[2][j][0], acc[2][j][1], 0, false);
                p = __builtin_amdgcn_cvt_pk_fp8_f32(acc[2][j][2], acc[2][j][3], p, true);
                pk.z = p;
                p = __builtin_amdgcn_cvt_pk_fp8_f32(acc[3][j][0], acc[3][j][1], 0, false);
                p = __builtin_amdgcn_cvt_pk_fp8_f32(acc[3][j][2], acc[3][j][3], p, true);
                pk.w = p;
                trans[((size_t)r * n_nodes + nds[j]) * 4 + quad] = pk;
            }
        }
    }
}

// 4 fp8 terms: acc += t * tanh(h*INV_SCALE + rel)   (t,h pre-scaled by SCALE)
__device__ __forceinline__ void term4(unsigned ut, unsigned uh, float4 r, float& acc) {
    f32x2 tlo = __builtin_amdgcn_cvt_pk_f32_fp8(ut, false);
    f32x2 thi = __builtin_amdgcn_cvt_pk_f32_fp8(ut, true);
    f32x2 hlo = __builtin_amdgcn_cvt_pk_f32_fp8(uh, false);
    f32x2 hhi = __builtin_amdgcn_cvt_pk_f32_fp8(uh, true);
    acc += tlo[0] * tanh_poly(fmaf(hlo[0], INV_SCALE, r.x));
    acc += tlo[1] * tanh_poly(fmaf(hlo[1], INV_SCALE, r.y));
    acc += thi[0] * tanh_poly(fmaf(hhi[0], INV_SCALE, r.z));
    acc += thi[1] * tanh_poly(fmaf(hhi[1], INV_SCALE, r.w));
}

// R17: COOPERATIVE 4-LANE GATHER. Diagnosis across R13..R16: per-CU time is
// pinned at ~22cyc/row regardless of concurrency (R14), L1 bypass (R15), or
// locality (R16: FETCH -32%, time unchanged). Model: each divergent wave-
// instruction = 64 separate 16B transactions -> 4 L1 lookups per 64B row;
// ~50K transactions/CU at ~5.6cyc each = the measured 280K cycles.
// Fix: 4-lane groups own one row; lane c loads bytes [16c,16c+16) -> the 4
// addresses are contiguous+64B-aligned and coalesce into ONE transaction
// (4x fewer). Row offsets distributed group-wide via __shfl from the holder
// lane; dot-product finished with shfl_xor(1),shfl_xor(2); result captured
// back by the holder with compile-time-predicated moves (no runtime reg
// indexing). Bucketing dropped (R16: +31us overhead, zero edge benefit).
// Wave = 128 edges: group g=lane>>2 computes edges wb+8g+k (k=0..7);
// lane 4g+c HOLDS indices for edges wb+8g+2c,+1 (holder of m: c=(m&7)>>1).
// Prediction: edge 117 -> 50-70us if transaction model right; unchanged ->
// coalesced and divergent transactions cost the same -> roofline.
__global__ __launch_bounds__(256)
void edge_coop_kernel(const unsigned* __restrict__ trans,
                      const float* __restrict__ relp,
                      const int* __restrict__ esrc, const int* __restrict__ edst,
                      const int* __restrict__ etype,
                      float* __restrict__ out, float* __restrict__ denom,
                      int E, int n_nodes) {
    const int tid  = threadIdx.x;
    const int lane = tid & 63;
    const int wid  = tid >> 6;
    const int wb   = blockIdx.x * 512 + wid * 128;
    const int c    = lane & 3;

    // Holder: this lane's two edges
    int e0 = wb + ((lane >> 2) << 3) + (c << 1);
    int e1 = e0 + 1;
    bool v0 = e0 < E, v1 = e1 < E;
    int i0 = v0 ? e0 : 0;
    int i1 = v1 ? e1 : 0;
    int t0 = etype[i0], s0 = esrc[i0], d0 = edst[i0];
    int t1 = etype[i1], s1 = esrc[i1], d1 = edst[i1];

    unsigned nn = (unsigned)n_nodes;
    unsigned rT0 = ((unsigned)t0 * nn + (unsigned)s0) * 64u;   // row byte offsets
    unsigned rH0 = ((unsigned)t0 * nn + (unsigned)d0) * 64u;
    unsigned rT1 = ((unsigned)t1 * nn + (unsigned)s1) * 64u;
    unsigned rH1 = ((unsigned)t1 * nn + (unsigned)d1) * 64u;

    const char* tbase = (const char*)trans;
    const int grp0 = lane & ~3;          // first lane of this group
    const unsigned cb = (unsigned)(c << 4);

    // Distribute row offsets + type for the group's 8 edges (k = 0..7)
    unsigned offT[8], offH[8];
    int tt[8];
    #pragma unroll
    for (int k = 0; k < 8; ++k) {
        int sl = grp0 + (k >> 1);
        offT[k] = (unsigned)__shfl((int)((k & 1) ? rT1 : rT0), sl, 64) + cb;
        offH[k] = (unsigned)__shfl((int)((k & 1) ? rH1 : rH0), sl, 64) + cb;
        tt[k]   = __shfl((k & 1) ? t1 : t0, sl, 64);
    }

    // Issue all 16 gathers (4 lanes x contiguous 16B per row -> 1 transaction)
    u32x4 T[8], H[8];
    #pragma unroll
    for (int k = 0; k < 8; ++k) {
        T[k] = *(const u32x4*)(tbase + offT[k]);
        H[k] = *(const u32x4*)(tbase + offH[k]);
    }

    float sum0 = 0.f, sum1 = 0.f;
    #pragma unroll
    for (int k = 0; k < 8; ++k) {
        const float4* pr = (const float4*)(relp + tt[k] * D64 + (c << 4));
        float a = 0.f;
        term4(T[k][0], H[k][0], pr[0], a);
        term4(T[k][1], H[k][1], pr[1], a);
        term4(T[k][2], H[k][2], pr[2], a);
        term4(T[k][3], H[k][3], pr[3], a);
        a += __shfl_xor(a, 1, 64);
        a += __shfl_xor(a, 2, 64);
        // holder of edge (..+k) is lane with c == (k>>1); slot k&1
        if (c == (k >> 1)) {
            if (k & 1) sum1 = a; else sum0 = a;
        }
    }

    if (v0) {
        float ex = __expf(sum0 * INV_SCALE);
        out[e0] = ex;
        atomicAdd(&denom[d0], ex);
    }
    if (v1) {
        float ex = __expf(sum1 * INV_SCALE);
        out[e1] = ex;
        atomicAdd(&denom[d1], ex);
    }
}

__global__ void normalize_kernel(float* __restrict__ out,
                                 const float* __restrict__ denom,
                                 const int* __restrict__ edst, int E) {
    int e = blockIdx.x * blockDim.x + threadIdx.x;
    if (e < E) out[e] = out[e] / denom[edst[e]];
}

// ---------------- fallback (R1 structure) if ws is too small ----------------
__global__ void zero_denom_kernel(float* __restrict__ denom, int n) {
    int i = blockIdx.x * blockDim.x + threadIdx.x;
    if (i < n) denom[i] = 0.0f;
}

__global__ __launch_bounds__(256)
void edge_att_fallback(const float* __restrict__ emb, const float* __restrict__ rel,
                       const float* __restrict__ WR, const int* __restrict__ esrc,
                       const int* __restrict__ edst, const int* __restrict__ etype,
                       float* __restrict__ exbuf, float* __restrict__ denom,
                       int E, int chunkSize) {
    const int type = blockIdx.x & 15;
    const int c    = blockIdx.x >> 4;
    const int lane = threadIdx.x & 63;
    const int wid  = threadIdx.x >> 6;
    long base0 = (long)c * (long)chunkSize;
    long cend  = base0 + chunkSize;
    if (cend > E) cend = E;
    if (base0 >= cend) return;
    int per = (chunkSize + 3) >> 2;
    long wbeg = base0 + (long)wid * per;
    long wend = wbeg + per;
    if (wend > cend) wend = cend;
    if (wbeg >= wend) return;
    float w[D64];
    const float* Wt = WR + (size_t)type * D64 * D64;
    #pragma unroll
    for (int d = 0; d < D64; ++d) w[d] = Wt[d * D64 + lane];
    const float rk = rel[type * D64 + lane];
    for (long s0 = wbeg; s0 < wend; s0 += 64) {
        long e = s0 + lane;
        int ty = -1, sv = 0, dv = 0;
        if (e < wend) { ty = etype[e]; sv = esrc[e]; dv = edst[e]; }
        unsigned long long m = __ballot(ty == type);
        while (m) {
            int b = __builtin_ctzll(m);
            m &= m - 1;
            int sn = __builtin_amdgcn_readlane(sv, b);
            int dn = __builtin_amdgcn_readlane(dv, b);
            const float4* es4 = (const float4*)(emb + (size_t)sn * D64);
            const float4* ed4 = (const float4*)(emb + (size_t)dn * D64);
            float t0 = 0.f, t1 = 0.f, t2 = 0.f, t3 = 0.f;
            float h0 = 0.f, h1 = 0.f, h2 = 0.f, h3 = 0.f;
            #pragma unroll
            for (int i = 0; i < D64 / 4; ++i) {
                float4 a = es4[i]; float4 b4 = ed4[i];
                t0 = fmaf(a.x, w[4*i+0], t0); t1 = fmaf(a.y, w[4*i+1], t1);
                t2 = fmaf(a.z, w[4*i+2], t2); t3 = fmaf(a.w, w[4*i+3], t3);
                h0 = fmaf(b4.x, w[4*i+0], h0); h1 = fmaf(b4.y, w[4*i+1], h1);
                h2 = fmaf(b4.z, w[4*i+2], h2); h3 = fmaf(b4.w, w[4*i+3], h3);
            }
            float t = (t0 + t1) + (t2 + t3);
            float h = (h0 + h1) + (h2 + h3);
            float p = t * tanh_fast(h + rk);
            #pragma unroll
            for (int off = 32; off > 0; off >>= 1) p += __shfl_xor(p, off);
            if (lane == 0) {
                float ex = __expf(p);
                exbuf[s0 + b] = ex;
                atomicAdd(&denom[dn], ex);
            }
        }
    }
}

__global__ void normalize_fallback(float* __restrict__ out,
                                   const float* __restrict__ denom,
                                   const int* __restrict__ edst, int E) {
    int e = blockIdx.x * blockDim.x + threadIdx.x;
    if (e < E) out[e] = out[e] / denom[edst[e]];
}
// ---------------------------------------------------------------------------

extern "C" void kernel_launch(void* const* d_in, const int* in_sizes, int n_in,
                              void* d_out, int out_size, void* d_ws, size_t ws_size,
                              hipStream_t stream) {
    const float* emb  = (const float*)d_in[0];   // [n_nodes, 64]
    const float* rel  = (const float*)d_in[1];   // [16, 64]
    const float* WR   = (const float*)d_in[2];   // [16, 64, 64]
    const int*   esrc = (const int*)d_in[3];     // [E]
    const int*   edst = (const int*)d_in[4];     // [E]
    const int*   ety  = (const int*)d_in[5];     // [E]

    const int E       = in_sizes[3];
    const int n_nodes = in_sizes[0] / D64;
    float* out = (float*)d_out;

    // workspace carve (256-B aligned) — same as the R7/R9/R13 (passing) layout
    size_t transB = (size_t)NREL * n_nodes * D64;            // fp8 bytes
    size_t off_trans = 0;
    size_t off_wt    = (off_trans + transB + 255) & ~(size_t)255;
    size_t off_rel   = (off_wt + (size_t)NREL * D64 * D64 * 2 + 255) & ~(size_t)255;
    size_t off_den   = (off_rel + (size_t)NREL * D64 * 4 + 255) & ~(size_t)255;
    size_t need      = off_den + (size_t)n_nodes * sizeof(float);

    if (ws_size >= need) {
        uint4*          trans = (uint4*)((char*)d_ws + off_trans);
        unsigned short* Wt    = (unsigned short*)((char*)d_ws + off_wt);
        float*          relp  = (float*)((char*)d_ws + off_rel);
        float*          denom = (float*)((char*)d_ws + off_den);

        int prepN = n_nodes > NREL * D64 * D64 ? n_nodes : NREL * D64 * D64;
        prep_kernel<<<(prepN + 255) / 256, 256, 0, stream>>>(WR, rel, Wt, relp,
                                                             denom, n_nodes);
        trans_gemm_kernel<<<((n_nodes + 255) / 256) * 2, 256, 0, stream>>>(emb, Wt, trans, n_nodes);
        edge_coop_kernel<<<(E + 511) / 512, 256, 0, stream>>>((const unsigned*)trans, relp,
                                                              esrc, edst, ety,
                                                              out, denom, E, n_nodes);
        normalize_kernel<<<(E + 255) / 256, 256, 0, stream>>>(out, denom, edst, E);
    } else {
        float* denom = (float*)d_ws;   // [n_nodes]
        zero_denom_kernel<<<(n_nodes + 255) / 256, 256, 0, stream>>>(denom, n_nodes);
        const int NCHUNK = 256;
        int chunk = (E + NCHUNK - 1) / NCHUNK;
        edge_att_fallback<<<16 * NCHUNK, 256, 0, stream>>>(emb, rel, WR, esrc, edst, ety,
                                                           out, denom, E, chunk);
        normalize_fallback<<<(E + 255) / 256, 256, 0, stream>>>(out, denom, edst, E);
    }
}